// Round 5
// baseline (404.271 us; speedup 1.0000x reference)
//
#include <hip/hip_runtime.h>

typedef __bf16 bf16x8 __attribute__((ext_vector_type(8)));
typedef float f32x4 __attribute__((ext_vector_type(4)));

__device__ __forceinline__ unsigned short f2bf(float f) {
    unsigned int u = __float_as_uint(f);
    unsigned int r = (u + 0x7FFFu + ((u >> 16) & 1u)) >> 16;
    return (unsigned short)r;
}

__device__ __forceinline__ void gload16(const void* g, void* l) {
    __builtin_amdgcn_global_load_lds(
        (const __attribute__((address_space(1))) unsigned int*)g,
        (__attribute__((address_space(3))) unsigned int*)l, 16, 0, 0);
}

__device__ __forceinline__ void barrier_raw() {
    asm volatile("" ::: "memory");
    __builtin_amdgcn_s_barrier();
    asm volatile("" ::: "memory");
}

__device__ __forceinline__ void vmwait0() {
    asm volatile("s_waitcnt vmcnt(0)" ::: "memory");
}

__device__ __forceinline__ float gelu_fast(float u) {
    float z = 1.595769122f * u + 0.071354816f * u * u * u;
    return u / (1.f + __expf(-z));
}

// ---------------- weight convert: fp32 -> bf16, 4 elems/thread ----------------
__global__ __launch_bounds__(256) void f2b4(const float* __restrict__ in,
                                            unsigned short* __restrict__ out) {
    size_t i = ((size_t)blockIdx.x * 256 + threadIdx.x) * 4;
    float4 v = *(const float4*)(in + i);
    ushort4 o;
    o.x = f2bf(v.x); o.y = f2bf(v.y); o.z = f2bf(v.z); o.w = f2bf(v.w);
    *(ushort4*)(out + i) = o;
}

// ------------- transpose + convert: fp32 [R][C] -> bf16 [C][R] ---------------
__global__ __launch_bounds__(256) void transpose_f2b(const float* __restrict__ in,
                                                     unsigned short* __restrict__ out,
                                                     int R, int C) {
    __shared__ float tile[32][33];
    int r0 = blockIdx.y * 32, c0 = blockIdx.x * 32;
    int tx = threadIdx.x & 31, ty = threadIdx.x >> 5;
#pragma unroll
    for (int i = 0; i < 4; i++) {
        int r = ty + i * 8;
        tile[r][tx] = in[(size_t)(r0 + r) * C + c0 + tx];
    }
    __syncthreads();
#pragma unroll
    for (int i = 0; i < 4; i++) {
        int r = ty + i * 8;
        out[(size_t)(c0 + r) * R + r0 + tx] = f2bf(tile[tx][r]);
    }
}

// ------- V transpose: qkv cols [2048..3072) per head -> vt[head][128][1024] -------
__global__ __launch_bounds__(256) void transpose_v(const unsigned short* __restrict__ qkv,
                                                   unsigned short* __restrict__ vt) {
    __shared__ unsigned short tile[32][33];
    int head = blockIdx.z;
    int b = head >> 3;
    int n0 = blockIdx.x * 32, d0 = blockIdx.y * 32;
    int tx = threadIdx.x & 31, ty = threadIdx.x >> 5;
    const unsigned short* src = qkv + (size_t)(b * 1024) * 3072 + 2048 + (head & 7) * 128;
#pragma unroll
    for (int i = 0; i < 4; i++) {
        int n = ty + i * 8;
        tile[n][tx] = src[(size_t)(n0 + n) * 3072 + d0 + tx];
    }
    __syncthreads();
#pragma unroll
    for (int i = 0; i < 4; i++) {
        int d = ty + i * 8;
        vt[((size_t)head * 128 + d0 + d) * 1024 + n0 + tx] = tile[tx][d];
    }
}

// -------- ada modulation, split-K --------
__global__ __launch_bounds__(256) void ada_mod_part(const float* __restrict__ c,
                                                    const float* __restrict__ W,
                                                    float* __restrict__ partial) {
    __shared__ float sc[8 * 64];
    int kc = blockIdx.y * 64;
    for (int i = threadIdx.x; i < 512; i += 256) {
        int b = i >> 6, k = i & 63;
        float cv = c[b * 1024 + kc + k];
        sc[i] = cv / (1.f + __expf(-cv));
    }
    __syncthreads();
    int j = blockIdx.x * 256 + threadIdx.x;
    float acc[8] = {0, 0, 0, 0, 0, 0, 0, 0};
    for (int k = 0; k < 64; k++) {
        float w = W[(size_t)(kc + k) * 3072 + j];
#pragma unroll
        for (int b = 0; b < 8; b++) acc[b] += sc[b * 64 + k] * w;
    }
#pragma unroll
    for (int b = 0; b < 8; b++) partial[((size_t)blockIdx.y * 8 + b) * 3072 + j] = acc[b];
}

__global__ __launch_bounds__(256) void ada_reduce(const float* __restrict__ partial,
                                                  const float* __restrict__ bias,
                                                  float* __restrict__ out) {
    int idx = blockIdx.x * 256 + threadIdx.x;
    int b = idx / 3072;
    int jj = idx - b * 3072;
    float s = bias[jj];
#pragma unroll
    for (int ch = 0; ch < 16; ch++) s += partial[((size_t)ch * 8 + b) * 3072 + jj];
    out[idx] = s;
}

// -------- LN + adaLN modulate: fp32 row -> bf16 row --------
__global__ __launch_bounds__(256) void ln_mod_kernel(const float* __restrict__ x,
                                                     const float* __restrict__ gamma,
                                                     const float* __restrict__ beta,
                                                     const float* __restrict__ mods,
                                                     unsigned short* __restrict__ out) {
    int row = blockIdx.x;
    int b = row >> 10;
    float4 v = ((const float4*)(x + (size_t)row * 1024))[threadIdx.x];
    float s = v.x + v.y + v.z + v.w;
    float s2 = v.x * v.x + v.y * v.y + v.z * v.z + v.w * v.w;
#pragma unroll
    for (int d = 1; d < 64; d <<= 1) { s += __shfl_xor(s, d); s2 += __shfl_xor(s2, d); }
    __shared__ float red[8];
    int lane = threadIdx.x & 63, wid = threadIdx.x >> 6;
    if (lane == 0) { red[wid] = s; red[4 + wid] = s2; }
    __syncthreads();
    float S = red[0] + red[1] + red[2] + red[3];
    float S2 = red[4] + red[5] + red[6] + red[7];
    float mu = S * (1.f / 1024.f);
    float var = S2 * (1.f / 1024.f) - mu * mu;
    float rs = rsqrtf(var + 1e-6f);
    const float* mrow = mods + b * 3072;
    int j0 = threadIdx.x * 4;
    float hv[4] = {v.x, v.y, v.z, v.w};
    ushort4 o;
    unsigned short* op = (unsigned short*)&o;
#pragma unroll
    for (int i = 0; i < 4; i++) {
        int j = j0 + i;
        float hh = (hv[i] - mu) * rs * gamma[j] + beta[j];
        hh = hh * (1.f + mrow[1024 + j]) + mrow[j];
        op[i] = f2bf(hh);
    }
    *(ushort4*)(out + (size_t)row * 1024 + j0) = o;
}

// ================= BK=32 deep-prefetch GEMM =================
// C[M][N] = A[M][K] * Bt[N][K]^T.  BM=256, BN=NF*64, BK=32, 512 thr, WRxWC waves.
// 64B LDS rows -> fragment ds_read_b128 is bank-conflict-free with NO swizzle.
// Per K-tile: issue ALL next-tile global_load_lds first (full tile of latency
// cover), then ds_read frags, MFMA cluster, vmcnt(0) (nearly free), 1 barrier.
// EP: 0 = +bias -> bf16, 1 = x + gate*(acc+bias) -> fp32
//     2 = gelu(acc+bias) -> bf16, 3 = outf += gate*(acc+bias)
template <int NF, int WR, int WC, int EP>
__global__ __launch_bounds__(512) void gemmk(const unsigned short* __restrict__ A,
                                             const unsigned short* __restrict__ Bt,
                                             int N, int K, int nx,
                                             const float* __restrict__ bias,
                                             const float* __restrict__ xres,
                                             const float* __restrict__ mods,
                                             float* __restrict__ outf,
                                             unsigned short* __restrict__ outb) {
    constexpr int BROWS = NF * 64;
    constexpr int MR = 256 / (16 * WR);     // 8 (NF4) / 4 (NF2)
    constexpr int NR = BROWS / (16 * WC);   // 4
    constexpr int AE = 256 * 32;            // A elems per buffer
    constexpr int BE = BROWS * 32;
    extern __shared__ __align__(16) char smem[];
    __bf16* As = (__bf16*)smem;             // 2 x [256][32]
    __bf16* Bs = As + 2 * AE;               // 2 x [BROWS][32]

    int tid = threadIdx.x, lane = tid & 63, wid = tid >> 6;
    int wr = wid / WC, wc = wid % WC;
    int t = lane & 15, g = lane >> 4;

    // XCD-chunked block swizzle (grid divisible by 8)
    int nwg = gridDim.x, chunk = nwg >> 3;
    int swz = (blockIdx.x & 7) * chunk + (blockIdx.x >> 3);
    int bx = swz % nx, by = swz / nx;
    int rowA0 = by * 256, colB0 = bx * BROWS;

    int rin = tid >> 2, cq = (tid & 3) * 8;

    auto stage = [&](int nb, int kt1) {
        int k0 = kt1 << 5;
        gload16(A + (size_t)(rowA0 + rin) * K + k0 + cq, (void*)(As + nb * AE + tid * 8));
        gload16(A + (size_t)(rowA0 + 128 + rin) * K + k0 + cq,
                (void*)(As + nb * AE + 4096 + tid * 8));
        gload16(Bt + (size_t)(colB0 + rin) * K + k0 + cq, (void*)(Bs + nb * BE + tid * 8));
        if constexpr (NF == 4)
            gload16(Bt + (size_t)(colB0 + 128 + rin) * K + k0 + cq,
                    (void*)(Bs + nb * BE + 4096 + tid * 8));
    };

    f32x4 acc[MR][NR];
#pragma unroll
    for (int m = 0; m < MR; m++)
#pragma unroll
        for (int n = 0; n < NR; n++) acc[m][n] = (f32x4){0.f, 0.f, 0.f, 0.f};

    stage(0, 0);
    vmwait0();
    barrier_raw();

    int NT = K >> 5;
#pragma unroll 1
    for (int kt = 0; kt < NT; ++kt) {
        const __bf16* Ac = As + (kt & 1) * AE;
        const __bf16* Bc = Bs + (kt & 1) * BE;
        bool more = (kt + 1) < NT;
        if (more) stage((kt & 1) ^ 1, kt + 1);   // issue early: full tile of cover

        bf16x8 a[MR], b[NR];
#pragma unroll
        for (int m = 0; m < MR; m++)
            a[m] = *(const bf16x8*)&Ac[(wr * (MR * 16) + m * 16 + t) * 32 + g * 8];
#pragma unroll
        for (int n = 0; n < NR; n++)
            b[n] = *(const bf16x8*)&Bc[(wc * (NR * 16) + n * 16 + t) * 32 + g * 8];

        __builtin_amdgcn_s_setprio(1);
#pragma unroll
        for (int m = 0; m < MR; m++)
#pragma unroll
            for (int n = 0; n < NR; n++)
                acc[m][n] = __builtin_amdgcn_mfma_f32_16x16x32_bf16(a[m], b[n], acc[m][n], 0, 0, 0);
        __builtin_amdgcn_s_setprio(0);

        if (more) {
            vmwait0();
            barrier_raw();
        }
    }

    // ---- epilogue ----
    int row0 = rowA0 + wr * (MR * 16), col0 = colB0 + wc * (NR * 16);
#pragma unroll
    for (int m = 0; m < MR; m++)
#pragma unroll
        for (int n = 0; n < NR; n++) {
            int col = col0 + n * 16 + t;
#pragma unroll
            for (int r = 0; r < 4; r++) {
                int row = row0 + m * 16 + g * 4 + r;
                float v = acc[m][n][r];
                if (EP == 0) {
                    outb[(size_t)row * N + col] = f2bf(v + bias[col]);
                } else if (EP == 1) {
                    int bb = row >> 10;
                    float gt = mods[bb * 3072 + 2048 + col];
                    outf[(size_t)row * 1024 + col] =
                        xres[(size_t)row * 1024 + col] + gt * (v + bias[col]);
                } else if (EP == 2) {
                    outb[(size_t)row * N + col] = f2bf(gelu_fast(v + bias[col]));
                } else {
                    int bb = row >> 10;
                    float gt = mods[bb * 3072 + 2048 + col];
                    outf[(size_t)row * 1024 + col] += gt * (v + bias[col]);
                }
            }
        }
}

// ======== flash attention, swapped-QK^T in-register softmax ========
__global__ __launch_bounds__(512, 4) void attn_kernel(const unsigned short* __restrict__ qkv,
                                                      const unsigned short* __restrict__ vt,
                                                      unsigned short* __restrict__ o) {
    extern __shared__ __align__(16) char asmem[];
    __bf16* Ks = (__bf16*)asmem;         // 2 x [64][128] swizzled
    __bf16* Vts = Ks + 2 * 64 * 128;     // 2 x [128][64] swizzled

    int bid = blockIdx.x;
    int logical = (bid & 7) * 64 + (bid >> 3);   // XCD swizzle (512 = 8*64)
    int q0 = (logical & 7) * 128;
    int bh = logical >> 3;
    int b = bh >> 3, h = bh & 7;
    int tid = threadIdx.x, lane = tid & 63, w = tid >> 6;
    int t = lane & 15, g = lane >> 4;
    int swzt = (t & 7) << 4;

    const unsigned short* qbase = qkv + (size_t)(b * 1024) * 3072 + h * 128;
    int qrow = q0 + w * 16 + t;
    bf16x8 qf[4];
#pragma unroll
    for (int ks = 0; ks < 4; ks++)
        qf[ks] = *(const bf16x8*)(qbase + (size_t)qrow * 3072 + ks * 32 + g * 8);

    f32x4 Oa[8];
#pragma unroll
    for (int n = 0; n < 8; n++) Oa[n] = (f32x4){0.f, 0.f, 0.f, 0.f};
    float m_r = -1e30f, l_r = 0.f;
    const float scale = 0.08838834764831845f;

    int krow = tid >> 4;
    int ksrc = (((tid & 15) * 16) ^ ((krow & 7) << 4)) >> 1;
    int vrow = tid >> 3;
    int vsrc = (((tid & 7) * 16) ^ ((vrow & 7) << 4)) >> 1;
    const unsigned short* vtg = vt + (size_t)bh * 128 * 1024;

    auto stage = [&](int buf, int kv0) {
        const unsigned short* kb = qkv + (size_t)(b * 1024 + kv0) * 3072 + 1024 + h * 128;
#pragma unroll
        for (int cc = 0; cc < 2; cc++) {
            gload16(kb + (size_t)(cc * 32 + krow) * 3072 + ksrc,
                    (void*)(Ks + buf * 8192 + cc * 4096 + tid * 8));
            gload16(vtg + (size_t)(cc * 64 + vrow) * 1024 + kv0 + vsrc,
                    (void*)(Vts + buf * 8192 + cc * 4096 + tid * 8));
        }
    };

    stage(0, 0);
    vmwait0();
    barrier_raw();

#pragma unroll 1
    for (int tile = 0; tile < 16; ++tile) {
        int cur = tile & 1;
        bool more = tile < 15;
        if (more) stage(cur ^ 1, (tile + 1) * 64);
        const __bf16* Kc = Ks + cur * 8192;
        const __bf16* Vc = Vts + cur * 8192;

        f32x4 St[4];
#pragma unroll
        for (int n = 0; n < 4; n++) St[n] = (f32x4){0.f, 0.f, 0.f, 0.f};
        __builtin_amdgcn_s_setprio(1);
#pragma unroll
        for (int ks = 0; ks < 4; ks++) {
#pragma unroll
            for (int n = 0; n < 4; n++) {
                bf16x8 kf = *(const bf16x8*)&Kc[(n * 16 + t) * 128 + (((ks * 64 + g * 16) ^ swzt) >> 1)];
                St[n] = __builtin_amdgcn_mfma_f32_16x16x32_bf16(kf, qf[ks], St[n], 0, 0, 0);
            }
        }
        __builtin_amdgcn_s_setprio(0);

        float mx = -1e30f;
#pragma unroll
        for (int n = 0; n < 4; n++)
#pragma unroll
            for (int r = 0; r < 4; r++) mx = fmaxf(mx, St[n][r]);
        mx *= scale;
        mx = fmaxf(mx, __shfl_xor(mx, 16));
        mx = fmaxf(mx, __shfl_xor(mx, 32));
        float mn = fmaxf(m_r, mx);
        float alpha = __expf(m_r - mn);
        m_r = mn;
        float p[4][4];
        float rs = 0.f;
#pragma unroll
        for (int n = 0; n < 4; n++)
#pragma unroll
            for (int r = 0; r < 4; r++) {
                float pv = __expf(St[n][r] * scale - mn);
                p[n][r] = pv;
                rs += pv;
            }
        rs += __shfl_xor(rs, 16);
        rs += __shfl_xor(rs, 32);
        l_r = l_r * alpha + rs;

        unsigned P01[4], P23[4];
#pragma unroll
        for (int n = 0; n < 4; n++) {
            P01[n] = (unsigned)f2bf(p[n][0]) | ((unsigned)f2bf(p[n][1]) << 16);
            P23[n] = (unsigned)f2bf(p[n][2]) | ((unsigned)f2bf(p[n][3]) << 16);
        }

#pragma unroll
        for (int r = 0; r < 4; r++) {
            float ar = __shfl(alpha, (lane & 48) + g * 4 + r);
#pragma unroll
            for (int n2 = 0; n2 < 8; n2++) Oa[n2][r] *= ar;
        }

#pragma unroll
        for (int ks2 = 0; ks2 < 2; ks2++) {
            int e = ks2 * 2, od = ks2 * 2 + 1;
            unsigned s16a = (g < 2) ? P01[e] : P01[od];
            unsigned s16b = (g < 2) ? P23[e] : P23[od];
            unsigned s32a = (g & 1) ? P01[e] : P01[od];
            unsigned s32b = (g & 1) ? P23[e] : P23[od];
            unsigned s48a = (g >= 2) ? P01[e] : P01[od];
            unsigned s48b = (g >= 2) ? P23[e] : P23[od];
            unsigned r16a = __shfl_xor(s16a, 16), r16b = __shfl_xor(s16b, 16);
            unsigned r32a = __shfl_xor(s32a, 32), r32b = __shfl_xor(s32b, 32);
            unsigned r48a = __shfl_xor(s48a, 48), r48b = __shfl_xor(s48b, 48);
            union { unsigned u[4]; bf16x8 v; } pa;
            pa.u[0] = (g == 0) ? P01[e] : (g == 1) ? r48a : (g == 2) ? r32a : r16a;
            pa.u[1] = (g == 0) ? P23[e] : (g == 1) ? r48b : (g == 2) ? r32b : r16b;
            pa.u[2] = (g == 0) ? r16a : (g == 1) ? r32a : (g == 2) ? r48a : P01[od];
            pa.u[3] = (g == 0) ? r16b : (g == 1) ? r32b : (g == 2) ? r48b : P23[od];
            __builtin_amdgcn_s_setprio(1);
#pragma unroll
            for (int n2 = 0; n2 < 8; n2++) {
                bf16x8 vf = *(const bf16x8*)&Vc[(n2 * 16 + t) * 64 + (((ks2 * 64 + g * 16) ^ swzt) >> 1)];
                Oa[n2] = __builtin_amdgcn_mfma_f32_16x16x32_bf16(pa.v, vf, Oa[n2], 0, 0, 0);
            }
            __builtin_amdgcn_s_setprio(0);
        }

        if (more) { vmwait0(); barrier_raw(); }
    }

#pragma unroll
    for (int r = 0; r < 4; r++) {
        float lq = __shfl(l_r, (lane & 48) + g * 4 + r);
        float inv = 1.f / lq;
        int orow = q0 + w * 16 + g * 4 + r;
#pragma unroll
        for (int n2 = 0; n2 < 8; n2++)
            o[(size_t)(b * 1024 + orow) * 1024 + h * 128 + n2 * 16 + t] = f2bf(Oa[n2][r] * inv);
    }
}

extern "C" void kernel_launch(void* const* d_in, const int* in_sizes, int n_in,
                              void* d_out, int out_size, void* d_ws, size_t ws_size,
                              hipStream_t stream) {
    const float* x          = (const float*)d_in[0];
    const float* c          = (const float*)d_in[1];
    const float* m_ada_w    = (const float*)d_in[2];
    const float* m_ada_b    = (const float*)d_in[3];
    const float* m_norm_g   = (const float*)d_in[4];
    const float* m_norm_b   = (const float*)d_in[5];
    const float* in_proj_w  = (const float*)d_in[6];
    const float* in_proj_b  = (const float*)d_in[7];
    const float* out_proj_w = (const float*)d_in[8];
    const float* out_proj_b = (const float*)d_in[9];
    const float* f_ada_w    = (const float*)d_in[10];
    const float* f_ada_b    = (const float*)d_in[11];
    const float* f_norm_g   = (const float*)d_in[12];
    const float* f_norm_b   = (const float*)d_in[13];
    const float* w1         = (const float*)d_in[14];
    const float* b1         = (const float*)d_in[15];
    const float* w2         = (const float*)d_in[16];
    const float* b2         = (const float*)d_in[17];
    float* out = (float*)d_out;
    char* ws = (char*)d_ws;

    unsigned short* Wq   = (unsigned short*)(ws + 0);          // 3072x1024 bf16
    unsigned short* Wo   = (unsigned short*)(ws + 6291456);    // 1024x1024
    unsigned short* vt   = (unsigned short*)(ws + 8388608);    // 64x128x1024 (later W1t/W2t)
    unsigned short* W1t  = (unsigned short*)(ws + 8388608);    // 4096x1024
    unsigned short* W2t  = (unsigned short*)(ws + 16777216);   // 1024x4096
    float*          modm = (float*)(ws + 25165824);            // 8x3072
    float*          modf = (float*)(ws + 25264128);            // 8x3072
    unsigned short* hbuf = (unsigned short*)(ws + 25362432);   // 8192x1024
    float*          part = (float*)(ws + 25362432);            // ada partials (hbuf region)
    float*          part2= (float*)(ws + 25362432 + 2097152);
    unsigned short* qkv  = (unsigned short*)(ws + 42139648);   // 8192x3072
    unsigned short* obuf = (unsigned short*)(ws + 92471296);   // 8192x1024
    unsigned short* h2   = (unsigned short*)(ws + 42139648);   // 8192x4096 (aliases qkv+obuf)

    hipFuncSetAttribute((const void*)&gemmk<4, 2, 4, 0>, hipFuncAttributeMaxDynamicSharedMemorySize, 65536);
    hipFuncSetAttribute((const void*)&gemmk<4, 2, 4, 2>, hipFuncAttributeMaxDynamicSharedMemorySize, 65536);
    hipFuncSetAttribute((const void*)&gemmk<2, 4, 2, 1>, hipFuncAttributeMaxDynamicSharedMemorySize, 49152);
    hipFuncSetAttribute((const void*)&gemmk<2, 4, 2, 3>, hipFuncAttributeMaxDynamicSharedMemorySize, 49152);
    hipFuncSetAttribute((const void*)&attn_kernel, hipFuncAttributeMaxDynamicSharedMemorySize, 65536);

    hipLaunchKernelGGL(ada_mod_part, dim3(12, 16), dim3(256), 0, stream, c, m_ada_w, part);
    hipLaunchKernelGGL(ada_mod_part, dim3(12, 16), dim3(256), 0, stream, c, f_ada_w, part2);
    hipLaunchKernelGGL(ada_reduce, dim3(96), dim3(256), 0, stream, part, m_ada_b, modm);
    hipLaunchKernelGGL(ada_reduce, dim3(96), dim3(256), 0, stream, part2, f_ada_b, modf);

    hipLaunchKernelGGL(f2b4, dim3(3072), dim3(256), 0, stream, in_proj_w, Wq);
    hipLaunchKernelGGL(f2b4, dim3(1024), dim3(256), 0, stream, out_proj_w, Wo);

    hipLaunchKernelGGL(ln_mod_kernel, dim3(8192), dim3(256), 0, stream, x, m_norm_g, m_norm_b, modm, hbuf);
    hipLaunchKernelGGL(HIP_KERNEL_NAME(gemmk<4, 2, 4, 0>), dim3(384), dim3(512), 65536, stream,
                       hbuf, Wq, 3072, 1024, 12, in_proj_b, (const float*)nullptr,
                       (const float*)nullptr, (float*)nullptr, qkv);
    hipLaunchKernelGGL(transpose_v, dim3(32, 4, 64), dim3(256), 0, stream, qkv, vt);
    hipLaunchKernelGGL(attn_kernel, dim3(512), dim3(512), 65536, stream, qkv, vt, obuf);
    hipLaunchKernelGGL(HIP_KERNEL_NAME(gemmk<2, 4, 2, 1>), dim3(256), dim3(512), 49152, stream,
                       obuf, Wo, 1024, 1024, 8, out_proj_b, x, modm, out, (unsigned short*)nullptr);

    hipLaunchKernelGGL(transpose_f2b, dim3(128, 32), dim3(256), 0, stream, w1, W1t, 1024, 4096);
    hipLaunchKernelGGL(transpose_f2b, dim3(32, 128), dim3(256), 0, stream, w2, W2t, 4096, 1024);

    hipLaunchKernelGGL(ln_mod_kernel, dim3(8192), dim3(256), 0, stream, out, f_norm_g, f_norm_b, modf, hbuf);
    hipLaunchKernelGGL(HIP_KERNEL_NAME(gemmk<4, 2, 4, 2>), dim3(512), dim3(512), 65536, stream,
                       hbuf, W1t, 4096, 1024, 16, b1, (const float*)nullptr,
                       (const float*)nullptr, (float*)nullptr, h2);
    hipLaunchKernelGGL(HIP_KERNEL_NAME(gemmk<2, 4, 2, 3>), dim3(256), dim3(512), 49152, stream,
                       h2, W2t, 1024, 4096, 8, b2, (const float*)nullptr, modf, out,
                       (unsigned short*)nullptr);
}

// Round 6
// 384.509 us; speedup vs baseline: 1.0514x; 1.0514x over previous
//
#include <hip/hip_runtime.h>

typedef __bf16 bf16x8 __attribute__((ext_vector_type(8)));
typedef float f32x4 __attribute__((ext_vector_type(4)));

__device__ __forceinline__ unsigned short f2bf(float f) {
    unsigned int u = __float_as_uint(f);
    unsigned int r = (u + 0x7FFFu + ((u >> 16) & 1u)) >> 16;
    return (unsigned short)r;
}

__device__ __forceinline__ void gload16(const void* g, void* l) {
    __builtin_amdgcn_global_load_lds(
        (const __attribute__((address_space(1))) unsigned int*)g,
        (__attribute__((address_space(3))) unsigned int*)l, 16, 0, 0);
}

__device__ __forceinline__ void barrier_raw() {
    asm volatile("" ::: "memory");
    __builtin_amdgcn_s_barrier();
    asm volatile("" ::: "memory");
}

__device__ __forceinline__ void lgkm0_fence() {
    asm volatile("s_waitcnt lgkmcnt(0)" ::: "memory");
    __builtin_amdgcn_sched_barrier(0);
}

__device__ __forceinline__ float gelu_fast(float u) {
    float z = 1.595769122f * u + 0.071354816f * u * u * u;
    return u / (1.f + __expf(-z));
}

// ---------------- weight convert: fp32 -> bf16, 4 elems/thread ----------------
__global__ __launch_bounds__(256) void f2b4(const float* __restrict__ in,
                                            unsigned short* __restrict__ out) {
    size_t i = ((size_t)blockIdx.x * 256 + threadIdx.x) * 4;
    float4 v = *(const float4*)(in + i);
    ushort4 o;
    o.x = f2bf(v.x); o.y = f2bf(v.y); o.z = f2bf(v.z); o.w = f2bf(v.w);
    *(ushort4*)(out + i) = o;
}

// ------------- transpose + convert: fp32 [R][C] -> bf16 [C][R] ---------------
__global__ __launch_bounds__(256) void transpose_f2b(const float* __restrict__ in,
                                                     unsigned short* __restrict__ out,
                                                     int R, int C) {
    __shared__ float tile[32][33];
    int r0 = blockIdx.y * 32, c0 = blockIdx.x * 32;
    int tx = threadIdx.x & 31, ty = threadIdx.x >> 5;
#pragma unroll
    for (int i = 0; i < 4; i++) {
        int r = ty + i * 8;
        tile[r][tx] = in[(size_t)(r0 + r) * C + c0 + tx];
    }
    __syncthreads();
#pragma unroll
    for (int i = 0; i < 4; i++) {
        int r = ty + i * 8;
        out[(size_t)(c0 + r) * R + r0 + tx] = f2bf(tile[tx][r]);
    }
}

// ------- V transpose: qkv cols [2048..3072) per head -> vt[head][128][1024] -------
__global__ __launch_bounds__(256) void transpose_v(const unsigned short* __restrict__ qkv,
                                                   unsigned short* __restrict__ vt) {
    __shared__ unsigned short tile[32][33];
    int head = blockIdx.z;
    int b = head >> 3;
    int n0 = blockIdx.x * 32, d0 = blockIdx.y * 32;
    int tx = threadIdx.x & 31, ty = threadIdx.x >> 5;
    const unsigned short* src = qkv + (size_t)(b * 1024) * 3072 + 2048 + (head & 7) * 128;
#pragma unroll
    for (int i = 0; i < 4; i++) {
        int n = ty + i * 8;
        tile[n][tx] = src[(size_t)(n0 + n) * 3072 + d0 + tx];
    }
    __syncthreads();
#pragma unroll
    for (int i = 0; i < 4; i++) {
        int d = ty + i * 8;
        vt[((size_t)head * 128 + d0 + d) * 1024 + n0 + tx] = tile[tx][d];
    }
}

// -------- ada modulation, split-K --------
__global__ __launch_bounds__(256) void ada_mod_part(const float* __restrict__ c,
                                                    const float* __restrict__ W,
                                                    float* __restrict__ partial) {
    __shared__ float sc[8 * 64];
    int kc = blockIdx.y * 64;
    for (int i = threadIdx.x; i < 512; i += 256) {
        int b = i >> 6, k = i & 63;
        float cv = c[b * 1024 + kc + k];
        sc[i] = cv / (1.f + __expf(-cv));
    }
    __syncthreads();
    int j = blockIdx.x * 256 + threadIdx.x;
    float acc[8] = {0, 0, 0, 0, 0, 0, 0, 0};
    for (int k = 0; k < 64; k++) {
        float w = W[(size_t)(kc + k) * 3072 + j];
#pragma unroll
        for (int b = 0; b < 8; b++) acc[b] += sc[b * 64 + k] * w;
    }
#pragma unroll
    for (int b = 0; b < 8; b++) partial[((size_t)blockIdx.y * 8 + b) * 3072 + j] = acc[b];
}

__global__ __launch_bounds__(256) void ada_reduce(const float* __restrict__ partial,
                                                  const float* __restrict__ bias,
                                                  float* __restrict__ out) {
    int idx = blockIdx.x * 256 + threadIdx.x;
    int b = idx / 3072;
    int jj = idx - b * 3072;
    float s = bias[jj];
#pragma unroll
    for (int ch = 0; ch < 16; ch++) s += partial[((size_t)ch * 8 + b) * 3072 + jj];
    out[idx] = s;
}

// -------- LN + adaLN modulate: fp32 row -> bf16 row --------
__global__ __launch_bounds__(256) void ln_mod_kernel(const float* __restrict__ x,
                                                     const float* __restrict__ gamma,
                                                     const float* __restrict__ beta,
                                                     const float* __restrict__ mods,
                                                     unsigned short* __restrict__ out) {
    int row = blockIdx.x;
    int b = row >> 10;
    float4 v = ((const float4*)(x + (size_t)row * 1024))[threadIdx.x];
    float s = v.x + v.y + v.z + v.w;
    float s2 = v.x * v.x + v.y * v.y + v.z * v.z + v.w * v.w;
#pragma unroll
    for (int d = 1; d < 64; d <<= 1) { s += __shfl_xor(s, d); s2 += __shfl_xor(s2, d); }
    __shared__ float red[8];
    int lane = threadIdx.x & 63, wid = threadIdx.x >> 6;
    if (lane == 0) { red[wid] = s; red[4 + wid] = s2; }
    __syncthreads();
    float S = red[0] + red[1] + red[2] + red[3];
    float S2 = red[4] + red[5] + red[6] + red[7];
    float mu = S * (1.f / 1024.f);
    float var = S2 * (1.f / 1024.f) - mu * mu;
    float rs = rsqrtf(var + 1e-6f);
    const float* mrow = mods + b * 3072;
    int j0 = threadIdx.x * 4;
    float hv[4] = {v.x, v.y, v.z, v.w};
    ushort4 o;
    unsigned short* op = (unsigned short*)&o;
#pragma unroll
    for (int i = 0; i < 4; i++) {
        int j = j0 + i;
        float hh = (hv[i] - mu) * rs * gamma[j] + beta[j];
        hh = hh * (1.f + mrow[1024 + j]) + mrow[j];
        op[i] = f2bf(hh);
    }
    *(ushort4*)(out + (size_t)row * 1024 + j0) = o;
}

// ============ m201-style 8-phase GEMM, counted vmcnt ============
// C[M][N] = A[M][K] * Bt[N][K]^T.  BM=256, BN=NF*64, BK=64, 512 thr (2x4 waves).
// LDS: 2dbuf x 2half x (A 128x64 + B) bf16, 128B rows, 8x16B-slot XOR by (row&7)
// (r4-verified 0-conflict). Per K-tile: 4 phases, each {ds_read subtile ->
// stage 1 half-tile -> barrier -> lgkmcnt(0) -> 16 MFMA -> barrier}; quadrant
// order (0,0),(1,0),(0,1),(1,1); stage targets B1(kt+1)@p1, A0(kt+2)@p3,
// A1+B0(kt+2)@p4 (each slot fully read >=1 barrier before re-stage).
// ONE counted vmcnt per tile at p4 (3 half-tiles stay in flight).
// EP: 0 = +bias -> bf16, 1 = x + gate*(acc+bias) -> fp32
//     2 = gelu(acc+bias) -> bf16, 3 = outf += gate*(acc+bias)
template <int NF, int EP>
__global__ __launch_bounds__(512, 2) void gemm8p(const unsigned short* __restrict__ A,
                                                 const unsigned short* __restrict__ Bt,
                                                 int N, int K, int nx,
                                                 const float* __restrict__ bias,
                                                 const float* __restrict__ xres,
                                                 const float* __restrict__ mods,
                                                 float* __restrict__ outf,
                                                 unsigned short* __restrict__ outb) {
    constexpr int BN = NF * 64;
    constexpr int NH = NF / 2;              // b-frags per half-quadrant (2 or 1)
    constexpr int HA = 8192;                // elems per A half-tile (128x64)
    constexpr int HB = NF * 2048;           // elems per B half-tile
    constexpr int CIF = (NF == 4) ? 6 : 5;  // counted in-flight loads (3 halves)
    extern __shared__ __align__(16) char smem[];
    __bf16* As = (__bf16*)smem;             // [d*2+h] * HA
    __bf16* Bs = As + 4 * HA;               // [d*2+h] * HB

    int tid = threadIdx.x, lane = tid & 63, wid = tid >> 6;
    int wr = wid >> 2, wc = wid & 3;
    int t = lane & 15, g = lane >> 4;
    int xk = (t & 7) * 8;                   // element XOR for fragment reads

    int nwg = gridDim.x, chunk = nwg >> 3;
    int swz = (blockIdx.x & 7) * chunk + (blockIdx.x >> 3);
    int bx = swz % nx, by = swz / nx;
    int rowA0 = by * 256, colB0 = bx * BN;

    int rin = tid >> 3, cblk = tid & 7;
    int scol = (cblk ^ (rin & 7)) * 8;      // pre-swizzled global source col

    auto stageAh = [&](int d, int h, int kt) {
        int k0 = kt << 6;
        const unsigned short* src = A + (size_t)(rowA0 + h * 128 + rin) * K + k0 + scol;
        __bf16* dst = As + (d * 2 + h) * HA + tid * 8;
        gload16(src, dst);
        gload16(src + (size_t)64 * K, dst + 4096);
    };
    auto stageBh = [&](int d, int h, int kt) {
        int k0 = kt << 6;
        if constexpr (NF == 4) {
            const unsigned short* src = Bt + (size_t)(colB0 + h * 128 + rin) * K + k0 + scol;
            __bf16* dst = Bs + (d * 2 + h) * HB + tid * 8;
            gload16(src, dst);
            gload16(src + (size_t)64 * K, dst + 4096);
        } else {
            const unsigned short* src = Bt + (size_t)(colB0 + h * 64 + rin) * K + k0 + scol;
            gload16(src, Bs + (d * 2 + h) * HB + tid * 8);
        }
    };

    f32x4 acc[8][NF];
#pragma unroll
    for (int m = 0; m < 8; m++)
#pragma unroll
        for (int n = 0; n < NF; n++) acc[m][n] = (f32x4){0.f, 0.f, 0.f, 0.f};

    int NT = K >> 6;
    // prologue: tile0 (4 halves) + tile1 (A0, A1, B0)
    stageAh(0, 0, 0); stageAh(0, 1, 0); stageBh(0, 0, 0); stageBh(0, 1, 0);
    stageAh(1, 0, 1); stageAh(1, 1, 1); stageBh(1, 0, 1);
    asm volatile("s_waitcnt vmcnt(%0)" :: "i"(CIF) : "memory");
    barrier_raw();

#pragma unroll 1
    for (int kt = 0; kt < NT; ++kt) {
        int d = kt & 1, dn = d ^ 1;
        const __bf16* Ab = As + (d * 2 + wr) * HA;
        const __bf16* Bb = Bs + (d * 2 + (wc >> 1)) * HB;
        bool s1 = kt + 1 < NT, s2 = kt + 2 < NT;

        auto LDA = [&](int m, int ks) -> bf16x8 {
            return *(const bf16x8*)&Ab[(m * 16 + t) * 64 + ((ks * 32 + g * 8) ^ xk)];
        };
        auto LDB = [&](int n, int ks) -> bf16x8 {
            int row = (NF == 4 ? (wc & 1) * 64 : (wc & 1) * 32) + n * 16 + t;
            return *(const bf16x8*)&Bb[row * 64 + ((ks * 32 + g * 8) ^ xk)];
        };

        bf16x8 aF[4][2], aH[4][2], bL[NH][2], bH[NH][2];

        // ---- phase 1: quadrant (0,0); stage B1(kt+1) -> dbuf dn ----
#pragma unroll
        for (int m = 0; m < 4; m++) { aF[m][0] = LDA(m, 0); aF[m][1] = LDA(m, 1); }
#pragma unroll
        for (int n = 0; n < NH; n++) { bL[n][0] = LDB(n, 0); bL[n][1] = LDB(n, 1); }
        if (s1) stageBh(dn, 1, kt + 1);
        barrier_raw();
        lgkm0_fence();
        __builtin_amdgcn_s_setprio(1);
#pragma unroll
        for (int m = 0; m < 4; m++)
#pragma unroll
            for (int n = 0; n < NH; n++)
#pragma unroll
                for (int ks = 0; ks < 2; ks++)
                    acc[m][n] = __builtin_amdgcn_mfma_f32_16x16x32_bf16(aF[m][ks], bL[n][ks], acc[m][n], 0, 0, 0);
        __builtin_amdgcn_s_setprio(0);
        barrier_raw();

        // ---- phase 2: quadrant (1,0) ----
#pragma unroll
        for (int m = 0; m < 4; m++) { aH[m][0] = LDA(m + 4, 0); aH[m][1] = LDA(m + 4, 1); }
        barrier_raw();
        lgkm0_fence();
        __builtin_amdgcn_s_setprio(1);
#pragma unroll
        for (int m = 0; m < 4; m++)
#pragma unroll
            for (int n = 0; n < NH; n++)
#pragma unroll
                for (int ks = 0; ks < 2; ks++)
                    acc[m + 4][n] = __builtin_amdgcn_mfma_f32_16x16x32_bf16(aH[m][ks], bL[n][ks], acc[m + 4][n], 0, 0, 0);
        __builtin_amdgcn_s_setprio(0);
        barrier_raw();

        // ---- phase 3: quadrant (0,1); stage A0(kt+2) -> dbuf d ----
#pragma unroll
        for (int n = 0; n < NH; n++) { bH[n][0] = LDB(n + NH, 0); bH[n][1] = LDB(n + NH, 1); }
        if (s2) stageAh(d, 0, kt + 2);
        barrier_raw();
        lgkm0_fence();
        __builtin_amdgcn_s_setprio(1);
#pragma unroll
        for (int m = 0; m < 4; m++)
#pragma unroll
            for (int n = 0; n < NH; n++)
#pragma unroll
                for (int ks = 0; ks < 2; ks++)
                    acc[m][n + NH] = __builtin_amdgcn_mfma_f32_16x16x32_bf16(aF[m][ks], bH[n][ks], acc[m][n + NH], 0, 0, 0);
        __builtin_amdgcn_s_setprio(0);
        barrier_raw();

        // ---- phase 4: quadrant (1,1); stage A1+B0(kt+2) -> dbuf d; counted wait ----
        if (s2) { stageAh(d, 1, kt + 2); stageBh(d, 0, kt + 2); }
        __builtin_amdgcn_s_setprio(1);
#pragma unroll
        for (int m = 0; m < 4; m++)
#pragma unroll
            for (int n = 0; n < NH; n++)
#pragma unroll
                for (int ks = 0; ks < 2; ks++)
                    acc[m + 4][n + NH] = __builtin_amdgcn_mfma_f32_16x16x32_bf16(aH[m][ks], bH[n][ks], acc[m + 4][n + NH], 0, 0, 0);
        __builtin_amdgcn_s_setprio(0);
        if (s1) {
            if (s2) {
                asm volatile("s_waitcnt vmcnt(%0)" :: "i"(CIF) : "memory");
            } else {
                asm volatile("s_waitcnt vmcnt(0)" ::: "memory");
            }
            barrier_raw();
        }
    }

    // ---- epilogue ----
    int row0 = rowA0 + wr * 128, col0 = colB0 + wc * (NF * 16);
#pragma unroll
    for (int m = 0; m < 8; m++)
#pragma unroll
        for (int n = 0; n < NF; n++) {
            int col = col0 + n * 16 + t;
#pragma unroll
            for (int r = 0; r < 4; r++) {
                int row = row0 + m * 16 + g * 4 + r;
                float v = acc[m][n][r];
                if (EP == 0) {
                    outb[(size_t)row * N + col] = f2bf(v + bias[col]);
                } else if (EP == 1) {
                    int bb = row >> 10;
                    float gt = mods[bb * 3072 + 2048 + col];
                    outf[(size_t)row * 1024 + col] =
                        xres[(size_t)row * 1024 + col] + gt * (v + bias[col]);
                } else if (EP == 2) {
                    outb[(size_t)row * N + col] = f2bf(gelu_fast(v + bias[col]));
                } else {
                    int bb = row >> 10;
                    float gt = mods[bb * 3072 + 2048 + col];
                    outf[(size_t)row * 1024 + col] += gt * (v + bias[col]);
                }
            }
        }
}

// ======== flash attention, swapped-QK^T in-register softmax ========
__global__ __launch_bounds__(512, 4) void attn_kernel(const unsigned short* __restrict__ qkv,
                                                      const unsigned short* __restrict__ vt,
                                                      unsigned short* __restrict__ o) {
    extern __shared__ __align__(16) char asmem[];
    __bf16* Ks = (__bf16*)asmem;
    __bf16* Vts = Ks + 2 * 64 * 128;

    int bid = blockIdx.x;
    int logical = (bid & 7) * 64 + (bid >> 3);
    int q0 = (logical & 7) * 128;
    int bh = logical >> 3;
    int b = bh >> 3, h = bh & 7;
    int tid = threadIdx.x, lane = tid & 63, w = tid >> 6;
    int t = lane & 15, g = lane >> 4;
    int swzt = (t & 7) << 4;

    const unsigned short* qbase = qkv + (size_t)(b * 1024) * 3072 + h * 128;
    int qrow = q0 + w * 16 + t;
    bf16x8 qf[4];
#pragma unroll
    for (int ks = 0; ks < 4; ks++)
        qf[ks] = *(const bf16x8*)(qbase + (size_t)qrow * 3072 + ks * 32 + g * 8);

    f32x4 Oa[8];
#pragma unroll
    for (int n = 0; n < 8; n++) Oa[n] = (f32x4){0.f, 0.f, 0.f, 0.f};
    float m_r = -1e30f, l_r = 0.f;
    const float scale = 0.08838834764831845f;

    int krow = tid >> 4;
    int ksrc = (((tid & 15) * 16) ^ ((krow & 7) << 4)) >> 1;
    int vrow = tid >> 3;
    int vsrc = (((tid & 7) * 16) ^ ((vrow & 7) << 4)) >> 1;
    const unsigned short* vtg = vt + (size_t)bh * 128 * 1024;

    auto stage = [&](int buf, int kv0) {
        const unsigned short* kb = qkv + (size_t)(b * 1024 + kv0) * 3072 + 1024 + h * 128;
#pragma unroll
        for (int cc = 0; cc < 2; cc++) {
            gload16(kb + (size_t)(cc * 32 + krow) * 3072 + ksrc,
                    (void*)(Ks + buf * 8192 + cc * 4096 + tid * 8));
            gload16(vtg + (size_t)(cc * 64 + vrow) * 1024 + kv0 + vsrc,
                    (void*)(Vts + buf * 8192 + cc * 4096 + tid * 8));
        }
    };

    stage(0, 0);
    asm volatile("s_waitcnt vmcnt(0)" ::: "memory");
    barrier_raw();

#pragma unroll 1
    for (int tile = 0; tile < 16; ++tile) {
        int cur = tile & 1;
        bool more = tile < 15;
        if (more) stage(cur ^ 1, (tile + 1) * 64);
        const __bf16* Kc = Ks + cur * 8192;
        const __bf16* Vc = Vts + cur * 8192;

        f32x4 St[4];
#pragma unroll
        for (int n = 0; n < 4; n++) St[n] = (f32x4){0.f, 0.f, 0.f, 0.f};
        __builtin_amdgcn_s_setprio(1);
#pragma unroll
        for (int ks = 0; ks < 4; ks++) {
#pragma unroll
            for (int n = 0; n < 4; n++) {
                bf16x8 kf = *(const bf16x8*)&Kc[(n * 16 + t) * 128 + (((ks * 64 + g * 16) ^ swzt) >> 1)];
                St[n] = __builtin_amdgcn_mfma_f32_16x16x32_bf16(kf, qf[ks], St[n], 0, 0, 0);
            }
        }
        __builtin_amdgcn_s_setprio(0);

        float mx = -1e30f;
#pragma unroll
        for (int n = 0; n < 4; n++)
#pragma unroll
            for (int r = 0; r < 4; r++) mx = fmaxf(mx, St[n][r]);
        mx *= scale;
        mx = fmaxf(mx, __shfl_xor(mx, 16));
        mx = fmaxf(mx, __shfl_xor(mx, 32));
        float mn = fmaxf(m_r, mx);
        float alpha = __expf(m_r - mn);
        m_r = mn;
        float p[4][4];
        float rs = 0.f;
#pragma unroll
        for (int n = 0; n < 4; n++)
#pragma unroll
            for (int r = 0; r < 4; r++) {
                float pv = __expf(St[n][r] * scale - mn);
                p[n][r] = pv;
                rs += pv;
            }
        rs += __shfl_xor(rs, 16);
        rs += __shfl_xor(rs, 32);
        l_r = l_r * alpha + rs;

        unsigned P01[4], P23[4];
#pragma unroll
        for (int n = 0; n < 4; n++) {
            P01[n] = (unsigned)f2bf(p[n][0]) | ((unsigned)f2bf(p[n][1]) << 16);
            P23[n] = (unsigned)f2bf(p[n][2]) | ((unsigned)f2bf(p[n][3]) << 16);
        }

#pragma unroll
        for (int r = 0; r < 4; r++) {
            float ar = __shfl(alpha, (lane & 48) + g * 4 + r);
#pragma unroll
            for (int n2 = 0; n2 < 8; n2++) Oa[n2][r] *= ar;
        }

#pragma unroll
        for (int ks2 = 0; ks2 < 2; ks2++) {
            int e = ks2 * 2, od = ks2 * 2 + 1;
            unsigned s16a = (g < 2) ? P01[e] : P01[od];
            unsigned s16b = (g < 2) ? P23[e] : P23[od];
            unsigned s32a = (g & 1) ? P01[e] : P01[od];
            unsigned s32b = (g & 1) ? P23[e] : P23[od];
            unsigned s48a = (g >= 2) ? P01[e] : P01[od];
            unsigned s48b = (g >= 2) ? P23[e] : P23[od];
            unsigned r16a = __shfl_xor(s16a, 16), r16b = __shfl_xor(s16b, 16);
            unsigned r32a = __shfl_xor(s32a, 32), r32b = __shfl_xor(s32b, 32);
            unsigned r48a = __shfl_xor(s48a, 48), r48b = __shfl_xor(s48b, 48);
            union { unsigned u[4]; bf16x8 v; } pa;
            pa.u[0] = (g == 0) ? P01[e] : (g == 1) ? r48a : (g == 2) ? r32a : r16a;
            pa.u[1] = (g == 0) ? P23[e] : (g == 1) ? r48b : (g == 2) ? r32b : r16b;
            pa.u[2] = (g == 0) ? r16a : (g == 1) ? r32a : (g == 2) ? r48a : P01[od];
            pa.u[3] = (g == 0) ? r16b : (g == 1) ? r32b : (g == 2) ? r48b : P23[od];
            __builtin_amdgcn_s_setprio(1);
#pragma unroll
            for (int n2 = 0; n2 < 8; n2++) {
                bf16x8 vf = *(const bf16x8*)&Vc[(n2 * 16 + t) * 64 + (((ks2 * 64 + g * 16) ^ swzt) >> 1)];
                Oa[n2] = __builtin_amdgcn_mfma_f32_16x16x32_bf16(pa.v, vf, Oa[n2], 0, 0, 0);
            }
            __builtin_amdgcn_s_setprio(0);
        }

        if (more) {
            asm volatile("s_waitcnt vmcnt(0)" ::: "memory");
            barrier_raw();
        }
    }

#pragma unroll
    for (int r = 0; r < 4; r++) {
        float lq = __shfl(l_r, (lane & 48) + g * 4 + r);
        float inv = 1.f / lq;
        int orow = q0 + w * 16 + g * 4 + r;
#pragma unroll
        for (int n2 = 0; n2 < 8; n2++)
            o[(size_t)(b * 1024 + orow) * 1024 + h * 128 + n2 * 16 + t] = f2bf(Oa[n2][r] * inv);
    }
}

extern "C" void kernel_launch(void* const* d_in, const int* in_sizes, int n_in,
                              void* d_out, int out_size, void* d_ws, size_t ws_size,
                              hipStream_t stream) {
    const float* x          = (const float*)d_in[0];
    const float* c          = (const float*)d_in[1];
    const float* m_ada_w    = (const float*)d_in[2];
    const float* m_ada_b    = (const float*)d_in[3];
    const float* m_norm_g   = (const float*)d_in[4];
    const float* m_norm_b   = (const float*)d_in[5];
    const float* in_proj_w  = (const float*)d_in[6];
    const float* in_proj_b  = (const float*)d_in[7];
    const float* out_proj_w = (const float*)d_in[8];
    const float* out_proj_b = (const float*)d_in[9];
    const float* f_ada_w    = (const float*)d_in[10];
    const float* f_ada_b    = (const float*)d_in[11];
    const float* f_norm_g   = (const float*)d_in[12];
    const float* f_norm_b   = (const float*)d_in[13];
    const float* w1         = (const float*)d_in[14];
    const float* b1         = (const float*)d_in[15];
    const float* w2         = (const float*)d_in[16];
    const float* b2         = (const float*)d_in[17];
    float* out = (float*)d_out;
    char* ws = (char*)d_ws;

    unsigned short* Wq   = (unsigned short*)(ws + 0);          // 3072x1024 bf16
    unsigned short* Wo   = (unsigned short*)(ws + 6291456);    // 1024x1024
    unsigned short* vt   = (unsigned short*)(ws + 8388608);    // 64x128x1024 (later W1t/W2t)
    unsigned short* W1t  = (unsigned short*)(ws + 8388608);    // 4096x1024
    unsigned short* W2t  = (unsigned short*)(ws + 16777216);   // 1024x4096
    float*          modm = (float*)(ws + 25165824);            // 8x3072
    float*          modf = (float*)(ws + 25264128);            // 8x3072
    unsigned short* hbuf = (unsigned short*)(ws + 25362432);   // 8192x1024
    float*          part = (float*)(ws + 25362432);            // ada partials (hbuf region)
    float*          part2= (float*)(ws + 25362432 + 2097152);
    unsigned short* qkv  = (unsigned short*)(ws + 42139648);   // 8192x3072
    unsigned short* obuf = (unsigned short*)(ws + 92471296);   // 8192x1024
    unsigned short* h2   = (unsigned short*)(ws + 42139648);   // 8192x4096 (aliases qkv+obuf)

    hipFuncSetAttribute((const void*)&gemm8p<4, 0>, hipFuncAttributeMaxDynamicSharedMemorySize, 131072);
    hipFuncSetAttribute((const void*)&gemm8p<4, 2>, hipFuncAttributeMaxDynamicSharedMemorySize, 131072);
    hipFuncSetAttribute((const void*)&gemm8p<2, 1>, hipFuncAttributeMaxDynamicSharedMemorySize, 98304);
    hipFuncSetAttribute((const void*)&gemm8p<2, 3>, hipFuncAttributeMaxDynamicSharedMemorySize, 98304);
    hipFuncSetAttribute((const void*)&attn_kernel, hipFuncAttributeMaxDynamicSharedMemorySize, 65536);

    hipLaunchKernelGGL(ada_mod_part, dim3(12, 16), dim3(256), 0, stream, c, m_ada_w, part);
    hipLaunchKernelGGL(ada_mod_part, dim3(12, 16), dim3(256), 0, stream, c, f_ada_w, part2);
    hipLaunchKernelGGL(ada_reduce, dim3(96), dim3(256), 0, stream, part, m_ada_b, modm);
    hipLaunchKernelGGL(ada_reduce, dim3(96), dim3(256), 0, stream, part2, f_ada_b, modf);

    hipLaunchKernelGGL(f2b4, dim3(3072), dim3(256), 0, stream, in_proj_w, Wq);
    hipLaunchKernelGGL(f2b4, dim3(1024), dim3(256), 0, stream, out_proj_w, Wo);

    hipLaunchKernelGGL(ln_mod_kernel, dim3(8192), dim3(256), 0, stream, x, m_norm_g, m_norm_b, modm, hbuf);
    hipLaunchKernelGGL(HIP_KERNEL_NAME(gemm8p<4, 0>), dim3(384), dim3(512), 131072, stream,
                       hbuf, Wq, 3072, 1024, 12, in_proj_b, (const float*)nullptr,
                       (const float*)nullptr, (float*)nullptr, qkv);
    hipLaunchKernelGGL(transpose_v, dim3(32, 4, 64), dim3(256), 0, stream, qkv, vt);
    hipLaunchKernelGGL(attn_kernel, dim3(512), dim3(512), 65536, stream, qkv, vt, obuf);
    hipLaunchKernelGGL(HIP_KERNEL_NAME(gemm8p<2, 1>), dim3(256), dim3(512), 98304, stream,
                       obuf, Wo, 1024, 1024, 8, out_proj_b, x, modm, out, (unsigned short*)nullptr);

    hipLaunchKernelGGL(transpose_f2b, dim3(128, 32), dim3(256), 0, stream, w1, W1t, 1024, 4096);
    hipLaunchKernelGGL(transpose_f2b, dim3(32, 128), dim3(256), 0, stream, w2, W2t, 4096, 1024);

    hipLaunchKernelGGL(ln_mod_kernel, dim3(8192), dim3(256), 0, stream, out, f_norm_g, f_norm_b, modf, hbuf);
    hipLaunchKernelGGL(HIP_KERNEL_NAME(gemm8p<4, 2>), dim3(512), dim3(512), 131072, stream,
                       hbuf, W1t, 4096, 1024, 16, b1, (const float*)nullptr,
                       (const float*)nullptr, (float*)nullptr, h2);
    hipLaunchKernelGGL(HIP_KERNEL_NAME(gemm8p<2, 3>), dim3(256), dim3(512), 98304, stream,
                       h2, W2t, 1024, 4096, 8, b2, (const float*)nullptr, modf, out,
                       (unsigned short*)nullptr);
}